// Round 6
// baseline (380.769 us; speedup 1.0000x reference)
//
#include <hip/hip_runtime.h>

// MemoryBank: B=16,C=256,H=W=64 -> T=65536 tokens; N=512 slots; SCALE=10.
// out = concat( z_recon [16,256,4096] , attn [65536,512] ) fp32.
//
// v2 = v1 + fix: P2b LDS swizzle removed. v1's key ((c>>1)&7)<<4 had bit 6
// but the 64B row only has offset bits 4-5 -> non-bijective map, rows
// c mod 16 >= 8 spilled into neighbor rows, colliding at 16-row boundaries
// (absmax 0.357 on recon, round 2). Linear is bank-balanced at the LDS
// data-volume floor for this access pattern (8 x 4B per bank per wave read),
// so no swizzle is needed at all.
// (Rounds 3-5: resubmit — GPU acquisition timeouts / container failure;
//  v2 has never executed.)
//
//   prep_k : mn = l2norm(memory) -> bf16 hi/lo [512][256]; memory^T -> bf16 hi/lo [256][512].
//   bank_k : 1024 blocks x 256 thr (4 waves), 64 tokens/block, 16 tokens/wave.
//     P0 : load z strip (exact fp32 row norms), build (10/||z||)*z A-frags as bf16 hi/lo.
//     P1 : 16 chunks of 32 slots: stage mn chunk in LDS (XOR swizzle -> bijective, 512B rows),
//          S = zn.mn^T via 3-term split MFMA (err ~1e-4 abs on |S|<=10),
//          p = exp(S - 10)  (10 is a provable row-max bound: cos<=1 -> no online max),
//          store unnormalized p into attn output, accumulate row sums.
//     P2a: attn *= 1/sum  in place (coalesced float4 RMW, block-private rows).
//     P2b: 16 chunks: stage mem^T chunk in LDS (linear); read p back from global directly
//          in B-frag layout (fp32 -> hi/lo); recon^T = mem^T x p^T via 3-term split.
//          D layout (row=c, col=token) makes [B,C,HW] stores coalesced - no transpose.

#define HW     4096
#define CC     256
#define NS     512
#define TT     64          // tokens per block
#define NCH    32          // slots per chunk
#define NCHUNK (NS / NCH)

typedef float          f32x4  __attribute__((ext_vector_type(4)));
typedef __bf16         bf16x8 __attribute__((ext_vector_type(8)));
typedef unsigned short u16x8  __attribute__((ext_vector_type(8)));

static __device__ __forceinline__ unsigned short f2bf(float x) {
    unsigned u = __float_as_uint(x);
    u += 0x7FFFu + ((u >> 16) & 1u);          // round-to-nearest-even
    return (unsigned short)(u >> 16);
}
static __device__ __forceinline__ float bf2f(unsigned short b) {
    return __uint_as_float(((unsigned)b) << 16);
}
static __device__ __forceinline__ f32x4 mfma16(u16x8 a, u16x8 b, f32x4 c) {
    return __builtin_amdgcn_mfma_f32_16x16x32_bf16(
        __builtin_bit_cast(bf16x8, a), __builtin_bit_cast(bf16x8, b), c, 0, 0, 0);
}

// ---------------------------------------------------------------- prep ----
__global__ __launch_bounds__(64) void prep_k(
    const float* __restrict__ mem,
    unsigned short* __restrict__ mn_hi, unsigned short* __restrict__ mn_lo,
    unsigned short* __restrict__ mT_hi, unsigned short* __restrict__ mT_lo)
{
    const int n = blockIdx.x;          // slot
    const int lane = threadIdx.x;      // 0..63, 4 channels each
    float4 v = *(const float4*)(mem + n * CC + lane * 4);
    float ss = v.x * v.x + v.y * v.y + v.z * v.z + v.w * v.w;
    #pragma unroll
    for (int off = 1; off < 64; off <<= 1) ss += __shfl_xor(ss, off);
    const float inv = 1.0f / fmaxf(sqrtf(ss), 1e-12f);   // matches F.normalize eps
    float raw[4] = {v.x, v.y, v.z, v.w};
    #pragma unroll
    for (int k = 0; k < 4; ++k) {
        int c = lane * 4 + k;
        float r = raw[k];
        unsigned short rh = f2bf(r);
        unsigned short rl = f2bf(r - bf2f(rh));
        float nv = r * inv;
        unsigned short nh = f2bf(nv);
        unsigned short nl = f2bf(nv - bf2f(nh));
        mn_hi[n * CC + c] = nh;        // normalized keys, row-major [n][c]
        mn_lo[n * CC + c] = nl;
        mT_hi[c * NS + n] = rh;        // raw memory transposed [c][n]
        mT_lo[c * NS + n] = rl;
    }
}

// ---------------------------------------------------------------- main ----
__global__ __launch_bounds__(256, 4) void bank_k(
    const float* __restrict__ z,
    const unsigned short* __restrict__ mn_hi, const unsigned short* __restrict__ mn_lo,
    const unsigned short* __restrict__ mT_hi, const unsigned short* __restrict__ mT_lo,
    float* __restrict__ out_recon, float* __restrict__ out_attn)
{
    __shared__ unsigned short s_a[NCH * CC];   // 16 KB: hi chunk (mn | memT)
    __shared__ unsigned short s_b[NCH * CC];   // 16 KB: lo chunk
    __shared__ float s_invsum[TT];

    const int tid  = threadIdx.x;
    const int wave = tid >> 6;
    const int lane = tid & 63;
    const int col  = lane & 15;        // A-row / B-col / D-col lane index
    const int g    = lane >> 4;        // k-group (0..3)

    const int t_base = blockIdx.x * TT;         // 64 tokens, never straddles a batch
    const int bidx   = t_base / HW;
    const int hw0    = t_base % HW;
    const int t0     = wave * 16;               // wave's token offset in block

    // ---- P0: z strip -> A-frags (bf16 hi/lo), exact fp32 norm ----
    const float* zp = z + (size_t)bidx * CC * HW + hw0 + t0 + col;
    u16x8 za_h[8], za_l[8];
    float ss = 0.0f;
    #pragma unroll
    for (int kt = 0; kt < 8; ++kt) {
        #pragma unroll
        for (int j = 0; j < 8; ++j) {
            float v = zp[(size_t)(kt * 32 + g * 8 + j) * HW];
            ss += v * v;
            unsigned short h = f2bf(v);            // unscaled split (pre-norm)
            za_h[kt][j] = h;
            za_l[kt][j] = f2bf(v - bf2f(h));
        }
    }
    ss += __shfl_xor(ss, 16);
    ss += __shfl_xor(ss, 32);
    const float sc = 10.0f / fmaxf(sqrtf(ss), 1e-12f);  // fold SCALE into zn
    #pragma unroll
    for (int kt = 0; kt < 8; ++kt) {
        #pragma unroll
        for (int j = 0; j < 8; ++j) {               // rescale + re-split (err ~2^-15)
            float v = (bf2f(za_h[kt][j]) + bf2f(za_l[kt][j])) * sc;
            unsigned short h = f2bf(v);
            za_h[kt][j] = h;
            za_l[kt][j] = f2bf(v - bf2f(h));
        }
    }

    // ---- P1: scores + unnormalized exp + row sums ----
    float sum4[4] = {0.f, 0.f, 0.f, 0.f};
    for (int ch = 0; ch < NCHUNK; ++ch) {
        __syncthreads();                            // protect prev chunk reads
        #pragma unroll
        for (int it = 0; it < 4; ++it) {            // 1024 16B units, 256 thr
            int u  = tid + it * 256;
            int n  = u >> 5;                        // chunk slot row 0..31
            int cb = (u & 31) << 4;                 // byte col 0..496 (bits 4-8)
            int d  = n * 512 + (cb ^ ((n & 7) << 4));   // key bits 4-6: bijective
            *(u16x8*)((char*)s_a + d) =
                *(const u16x8*)((const char*)(mn_hi + (size_t)(ch * NCH + n) * CC) + cb);
            *(u16x8*)((char*)s_b + d) =
                *(const u16x8*)((const char*)(mn_lo + (size_t)(ch * NCH + n) * CC) + cb);
        }
        __syncthreads();
        f32x4 acc0 = {0.f, 0.f, 0.f, 0.f}, acc1 = acc0;
        const int r0 = col, r1 = 16 + col;          // B-frag LDS rows (slot-local)
        const int sw = (col & 7) << 4;              // (16+col)&7 == col&7
        #pragma unroll
        for (int kt = 0; kt < 8; ++kt) {
            int cb = kt * 64 + g * 16;
            u16x8 bh0 = *(const u16x8*)((const char*)s_a + r0 * 512 + (cb ^ sw));
            u16x8 bh1 = *(const u16x8*)((const char*)s_a + r1 * 512 + (cb ^ sw));
            u16x8 bl0 = *(const u16x8*)((const char*)s_b + r0 * 512 + (cb ^ sw));
            u16x8 bl1 = *(const u16x8*)((const char*)s_b + r1 * 512 + (cb ^ sw));
            acc0 = mfma16(za_h[kt], bh0, acc0);     // 3-term Markidis split
            acc1 = mfma16(za_h[kt], bh1, acc1);
            acc0 = mfma16(za_h[kt], bl0, acc0);
            acc1 = mfma16(za_h[kt], bl1, acc1);
            acc0 = mfma16(za_l[kt], bh0, acc0);
            acc1 = mfma16(za_l[kt], bh1, acc1);
        }
        #pragma unroll
        for (int r = 0; r < 4; ++r) {               // D row = 4g+r (token), col = slot
            float p0 = __expf(acc0[r] - 10.0f);     // s<=10 provably -> stable
            float p1 = __expf(acc1[r] - 10.0f);
            size_t arow = (size_t)(t_base + t0 + 4 * g + r) * NS + ch * NCH;
            out_attn[arow + col]      = p0;         // 64B-coalesced per 16-lane group
            out_attn[arow + 16 + col] = p1;
            sum4[r] += p0 + p1;
        }
    }
    #pragma unroll
    for (int r = 0; r < 4; ++r) {                   // reduce over the 16 D-cols
        float s = sum4[r];
        s += __shfl_xor(s, 1); s += __shfl_xor(s, 2);
        s += __shfl_xor(s, 4); s += __shfl_xor(s, 8);
        if (col == 0) s_invsum[t0 + 4 * g + r] = 1.0f / s;
    }
    __syncthreads();

    // ---- P2a: normalize attn in place (block-private rows, coalesced) ----
    {
        float4* a4 = (float4*)(out_attn + (size_t)t_base * NS);
        for (int i = tid; i < TT * NS / 4; i += 256) {
            float is = s_invsum[i >> 7];            // 128 float4 per token row
            float4 v = a4[i];
            v.x *= is; v.y *= is; v.z *= is; v.w *= is;
            a4[i] = v;
        }
    }
    __syncthreads();                                // writes visible to P2b reads

    // ---- P2b: recon^T = mem^T x p^T ----
    f32x4 racc[16];
    const f32x4 fz = {0.f, 0.f, 0.f, 0.f};
    #pragma unroll
    for (int ct = 0; ct < 16; ++ct) racc[ct] = fz;

    const float* prow = out_attn + (size_t)(t_base + t0 + col) * NS;
    for (int ch = 0; ch < NCHUNK; ++ch) {
        __syncthreads();
        #pragma unroll
        for (int it = 0; it < 4; ++it) {            // stage memT chunk [256 c][32 n], LINEAR
            int u   = tid + it * 256;
            int c   = u >> 2;
            int off = (u & 3) << 4;
            int d   = c * 64 + off;                 // v2 fix: no swizzle (64B row has
                                                    // only offset bits 4-5; any 3-bit
                                                    // key is non-bijective). Linear is
                                                    // at the LDS volume floor anyway.
            *(u16x8*)((char*)s_a + d) =
                *(const u16x8*)((const char*)(mT_hi + (size_t)c * NS + ch * NCH) + off);
            *(u16x8*)((char*)s_b + d) =
                *(const u16x8*)((const char*)(mT_lo + (size_t)c * NS + ch * NCH) + off);
        }
        __syncthreads();
        // p B-frag: B[k=n][j=token]; token=col, n=g*8+i -> 32B contiguous read
        float4 pv0 = *(const float4*)(prow + ch * NCH + g * 8);
        float4 pv1 = *(const float4*)(prow + ch * NCH + g * 8 + 4);
        float pv[8] = {pv0.x, pv0.y, pv0.z, pv0.w, pv1.x, pv1.y, pv1.z, pv1.w};
        u16x8 pbh, pbl;
        #pragma unroll
        for (int j = 0; j < 8; ++j) {
            unsigned short h = f2bf(pv[j]);
            pbh[j] = h;
            pbl[j] = f2bf(pv[j] - bf2f(h));
        }
        #pragma unroll
        for (int ct = 0; ct < 16; ++ct) {
            int c = ct * 16 + col;                  // A row = c (memT), k = n
            int d = c * 64 + g * 16;                // v2 fix: linear read (matches write)
            u16x8 mh = *(const u16x8*)((const char*)s_a + d);
            u16x8 ml = *(const u16x8*)((const char*)s_b + d);
            racc[ct] = mfma16(mh, pbh, racc[ct]);   // (mh+ml)(ph+pl) 3-term
            racc[ct] = mfma16(ml, pbh, racc[ct]);
            racc[ct] = mfma16(mh, pbl, racc[ct]);
        }
    }
    // D: row = c_local = 4g+r, col = token -> lanes span consecutive hw: coalesced
    float* rp = out_recon + (size_t)bidx * CC * HW + hw0 + t0 + col;
    #pragma unroll
    for (int ct = 0; ct < 16; ++ct) {
        #pragma unroll
        for (int r = 0; r < 4; ++r) {
            rp[(size_t)(ct * 16 + 4 * g + r) * HW] = racc[ct][r];
        }
    }
}

// -------------------------------------------------------------- launch ----
extern "C" void kernel_launch(void* const* d_in, const int* in_sizes, int n_in,
                              void* d_out, int out_size, void* d_ws, size_t ws_size,
                              hipStream_t stream) {
    (void)in_sizes; (void)n_in; (void)out_size; (void)ws_size;
    const float* zin = (const float*)d_in[0];
    const float* mem = (const float*)d_in[1];
    float* out_recon = (float*)d_out;
    float* out_attn  = (float*)d_out + (size_t)16 * 256 * 64 * 64;  // after z_recon

    // ws: 4 x [512*256] ushort = 1 MB
    unsigned short* mn_hi = (unsigned short*)d_ws;
    unsigned short* mn_lo = mn_hi + 512 * 256;
    unsigned short* mT_hi = mn_lo + 512 * 256;
    unsigned short* mT_lo = mT_hi + 512 * 256;

    prep_k<<<dim3(512), dim3(64), 0, stream>>>(mem, mn_hi, mn_lo, mT_hi, mT_lo);
    bank_k<<<dim3(65536 / TT), dim3(256), 0, stream>>>(
        zin, mn_hi, mn_lo, mT_hi, mT_lo, out_recon, out_attn);
}

// Round 8
// 366.485 us; speedup vs baseline: 1.0390x; 1.0390x over previous
//
#include <hip/hip_runtime.h>
#include <stdint.h>

// MemoryBank: B=16,C=256,H=W=64 -> T=65536 tokens; N=512 slots; SCALE=10.
// out = concat( z_recon [16,256,4096] , attn [65536,512] ) fp32.
//
// v3 = v2 + global_load_lds(width=16) staging (Common-mistake #1 / m97).
//   - P1: LDS dest now LINEAR; the bank-swizzle moved to the SOURCE address
//     (rule #21: same involution, key bits 4-6 within the 512B row -> lanes
//     permuted within the same cache lines; read-side XOR unchanged).
//   - P2b: staging was already lane-linear -> direct global_load_lds.
//   Removes 8 ds_writes + 8 VGPR round-trips + addr VALU per thread/chunk.
// v2 history: P2b swizzle removed (non-bijective in 64B rows; absmax 0.357
// round 2 -> 1.95e-3 round 6, PASSED, bank_k 206us, MfmaUtil 21%, VALU 19%,
// occupancy 41% -> latency-bound; this round targets the staging path).
// (Round 7: resubmit — container failed, v3 never ran.)

#define HW     4096
#define CC     256
#define NS     512
#define TT     64          // tokens per block
#define NCH    32          // slots per chunk
#define NCHUNK (NS / NCH)

typedef float          f32x4  __attribute__((ext_vector_type(4)));
typedef __bf16         bf16x8 __attribute__((ext_vector_type(8)));
typedef unsigned short u16x8  __attribute__((ext_vector_type(8)));

static __device__ __forceinline__ unsigned short f2bf(float x) {
    unsigned u = __float_as_uint(x);
    u += 0x7FFFu + ((u >> 16) & 1u);          // round-to-nearest-even
    return (unsigned short)(u >> 16);
}
static __device__ __forceinline__ float bf2f(unsigned short b) {
    return __uint_as_float(((unsigned)b) << 16);
}
static __device__ __forceinline__ f32x4 mfma16(u16x8 a, u16x8 b, f32x4 c) {
    return __builtin_amdgcn_mfma_f32_16x16x32_bf16(
        __builtin_bit_cast(bf16x8, a), __builtin_bit_cast(bf16x8, b), c, 0, 0, 0);
}
// async global->LDS, 16B per lane; LDS dest = wave-uniform base + lane*16
static __device__ __forceinline__ void g2l16(const void* g, void* l) {
    __builtin_amdgcn_global_load_lds(
        (const __attribute__((address_space(1))) uint32_t*)g,
        (__attribute__((address_space(3))) uint32_t*)l, 16, 0, 0);
}

// ---------------------------------------------------------------- prep ----
__global__ __launch_bounds__(64) void prep_k(
    const float* __restrict__ mem,
    unsigned short* __restrict__ mn_hi, unsigned short* __restrict__ mn_lo,
    unsigned short* __restrict__ mT_hi, unsigned short* __restrict__ mT_lo)
{
    const int n = blockIdx.x;          // slot
    const int lane = threadIdx.x;      // 0..63, 4 channels each
    float4 v = *(const float4*)(mem + n * CC + lane * 4);
    float ss = v.x * v.x + v.y * v.y + v.z * v.z + v.w * v.w;
    #pragma unroll
    for (int off = 1; off < 64; off <<= 1) ss += __shfl_xor(ss, off);
    const float inv = 1.0f / fmaxf(sqrtf(ss), 1e-12f);   // matches F.normalize eps
    float raw[4] = {v.x, v.y, v.z, v.w};
    #pragma unroll
    for (int k = 0; k < 4; ++k) {
        int c = lane * 4 + k;
        float r = raw[k];
        unsigned short rh = f2bf(r);
        unsigned short rl = f2bf(r - bf2f(rh));
        float nv = r * inv;
        unsigned short nh = f2bf(nv);
        unsigned short nl = f2bf(nv - bf2f(nh));
        mn_hi[n * CC + c] = nh;        // normalized keys, row-major [n][c]
        mn_lo[n * CC + c] = nl;
        mT_hi[c * NS + n] = rh;        // raw memory transposed [c][n]
        mT_lo[c * NS + n] = rl;
    }
}

// ---------------------------------------------------------------- main ----
__global__ __launch_bounds__(256, 4) void bank_k(
    const float* __restrict__ z,
    const unsigned short* __restrict__ mn_hi, const unsigned short* __restrict__ mn_lo,
    const unsigned short* __restrict__ mT_hi, const unsigned short* __restrict__ mT_lo,
    float* __restrict__ out_recon, float* __restrict__ out_attn)
{
    __shared__ unsigned short s_a[NCH * CC];   // 16 KB: hi chunk (mn | memT)
    __shared__ unsigned short s_b[NCH * CC];   // 16 KB: lo chunk
    __shared__ float s_invsum[TT];

    const int tid  = threadIdx.x;
    const int wave = tid >> 6;
    const int lane = tid & 63;
    const int col  = lane & 15;        // A-row / B-col / D-col lane index
    const int g    = lane >> 4;        // k-group (0..3)
    const int ln31 = lane & 31;
    const int rsel = lane >> 5;        // 0/1: which of the wave's 2 rows (P1 stage)

    const int t_base = blockIdx.x * TT;         // 64 tokens, never straddles a batch
    const int bidx   = t_base / HW;
    const int hw0    = t_base % HW;
    const int t0     = wave * 16;               // wave's token offset in block

    // ---- P0: z strip -> A-frags (bf16 hi/lo), exact fp32 norm ----
    const float* zp = z + (size_t)bidx * CC * HW + hw0 + t0 + col;
    u16x8 za_h[8], za_l[8];
    float ss = 0.0f;
    #pragma unroll
    for (int kt = 0; kt < 8; ++kt) {
        #pragma unroll
        for (int j = 0; j < 8; ++j) {
            float v = zp[(size_t)(kt * 32 + g * 8 + j) * HW];
            ss += v * v;
            unsigned short h = f2bf(v);            // unscaled split (pre-norm)
            za_h[kt][j] = h;
            za_l[kt][j] = f2bf(v - bf2f(h));
        }
    }
    ss += __shfl_xor(ss, 16);
    ss += __shfl_xor(ss, 32);
    const float sc = 10.0f / fmaxf(sqrtf(ss), 1e-12f);  // fold SCALE into zn
    #pragma unroll
    for (int kt = 0; kt < 8; ++kt) {
        #pragma unroll
        for (int j = 0; j < 8; ++j) {               // rescale + re-split (err ~2^-15)
            float v = (bf2f(za_h[kt][j]) + bf2f(za_l[kt][j])) * sc;
            unsigned short h = f2bf(v);
            za_h[kt][j] = h;
            za_l[kt][j] = f2bf(v - bf2f(h));
        }
    }

    // ---- P1: scores + unnormalized exp + row sums ----
    // Staging: per (wave,it) covers rows n0=wave*2+it*8, n0+1. LDS dest linear
    // (base + lane*16); source byte pre-swizzled cb ^ ((n&7)<<4) so the read
    // formula below (row*512 + (cb ^ ((row&7)<<4))) sees the right data.
    float sum4[4] = {0.f, 0.f, 0.f, 0.f};
    for (int ch = 0; ch < NCHUNK; ++ch) {
        __syncthreads();                            // protect prev chunk reads
        #pragma unroll
        for (int it = 0; it < 4; ++it) {
            const int n0 = wave * 2 + it * 8;       // wave-uniform
            const int n  = n0 + rsel;               // this lane's row
            const int gb = (ln31 << 4) ^ ((n & 7) << 4);   // swizzled src byte
            const char* gh = (const char*)(mn_hi + (size_t)(ch * NCH + n) * CC) + gb;
            const char* gl = (const char*)(mn_lo + (size_t)(ch * NCH + n) * CC) + gb;
            g2l16(gh, (char*)s_a + n0 * 512);
            g2l16(gl, (char*)s_b + n0 * 512);
        }
        __syncthreads();
        f32x4 acc0 = {0.f, 0.f, 0.f, 0.f}, acc1 = acc0;
        const int r0 = col, r1 = 16 + col;          // B-frag LDS rows (slot-local)
        const int sw = (col & 7) << 4;              // (16+col)&7 == col&7
        #pragma unroll
        for (int kt = 0; kt < 8; ++kt) {
            int cb = kt * 64 + g * 16;
            u16x8 bh0 = *(const u16x8*)((const char*)s_a + r0 * 512 + (cb ^ sw));
            u16x8 bh1 = *(const u16x8*)((const char*)s_a + r1 * 512 + (cb ^ sw));
            u16x8 bl0 = *(const u16x8*)((const char*)s_b + r0 * 512 + (cb ^ sw));
            u16x8 bl1 = *(const u16x8*)((const char*)s_b + r1 * 512 + (cb ^ sw));
            acc0 = mfma16(za_h[kt], bh0, acc0);     // 3-term Markidis split
            acc1 = mfma16(za_h[kt], bh1, acc1);
            acc0 = mfma16(za_h[kt], bl0, acc0);
            acc1 = mfma16(za_h[kt], bl1, acc1);
            acc0 = mfma16(za_l[kt], bh0, acc0);
            acc1 = mfma16(za_l[kt], bh1, acc1);
        }
        #pragma unroll
        for (int r = 0; r < 4; ++r) {               // D row = 4g+r (token), col = slot
            float p0 = __expf(acc0[r] - 10.0f);     // s<=10 provably -> stable
            float p1 = __expf(acc1[r] - 10.0f);
            size_t arow = (size_t)(t_base + t0 + 4 * g + r) * NS + ch * NCH;
            out_attn[arow + col]      = p0;         // 64B-coalesced per 16-lane group
            out_attn[arow + 16 + col] = p1;
            sum4[r] += p0 + p1;
        }
    }
    #pragma unroll
    for (int r = 0; r < 4; ++r) {                   // reduce over the 16 D-cols
        float s = sum4[r];
        s += __shfl_xor(s, 1); s += __shfl_xor(s, 2);
        s += __shfl_xor(s, 4); s += __shfl_xor(s, 8);
        if (col == 0) s_invsum[t0 + 4 * g + r] = 1.0f / s;
    }
    __syncthreads();

    // ---- P2a: normalize attn in place (block-private rows, coalesced) ----
    {
        float4* a4 = (float4*)(out_attn + (size_t)t_base * NS);
        for (int i = tid; i < TT * NS / 4; i += 256) {
            float is = s_invsum[i >> 7];            // 128 float4 per token row
            float4 v = a4[i];
            v.x *= is; v.y *= is; v.z *= is; v.w *= is;
            a4[i] = v;
        }
    }
    __syncthreads();                                // writes visible to P2b reads

    // ---- P2b: recon^T = mem^T x p^T ----
    f32x4 racc[16];
    const f32x4 fz = {0.f, 0.f, 0.f, 0.f};
    #pragma unroll
    for (int ct = 0; ct < 16; ++ct) racc[ct] = fz;

    const float* prow = out_attn + (size_t)(t_base + t0 + col) * NS;
    for (int ch = 0; ch < NCHUNK; ++ch) {
        __syncthreads();
        // stage memT chunk [256 c][32 n], lane-linear: c = wave*16+it*64+(lane>>2),
        // 64B per row, dest = c*64 + (lane&3)*16 = base + lane*16  ✓
        #pragma unroll
        for (int it = 0; it < 4; ++it) {
            const int c0 = wave * 16 + it * 64;     // wave-uniform row base
            const int c  = c0 + (lane >> 2);
            const int off = (lane & 3) << 4;
            const char* gh = (const char*)(mT_hi + (size_t)c * NS + ch * NCH) + off;
            const char* gl = (const char*)(mT_lo + (size_t)c * NS + ch * NCH) + off;
            g2l16(gh, (char*)s_a + c0 * 64);
            g2l16(gl, (char*)s_b + c0 * 64);
        }
        __syncthreads();
        // p B-frag: B[k=n][j=token]; token=col, n=g*8+i -> 32B contiguous read
        float4 pv0 = *(const float4*)(prow + ch * NCH + g * 8);
        float4 pv1 = *(const float4*)(prow + ch * NCH + g * 8 + 4);
        float pv[8] = {pv0.x, pv0.y, pv0.z, pv0.w, pv1.x, pv1.y, pv1.z, pv1.w};
        u16x8 pbh, pbl;
        #pragma unroll
        for (int j = 0; j < 8; ++j) {
            unsigned short h = f2bf(pv[j]);
            pbh[j] = h;
            pbl[j] = f2bf(pv[j] - bf2f(h));
        }
        #pragma unroll
        for (int ct = 0; ct < 16; ++ct) {
            int c = ct * 16 + col;                  // A row = c (memT), k = n
            int d = c * 64 + g * 16;                // linear (matches staging)
            u16x8 mh = *(const u16x8*)((const char*)s_a + d);
            u16x8 ml = *(const u16x8*)((const char*)s_b + d);
            racc[ct] = mfma16(mh, pbh, racc[ct]);   // (mh+ml)(ph+pl) 3-term
            racc[ct] = mfma16(ml, pbh, racc[ct]);
            racc[ct] = mfma16(mh, pbl, racc[ct]);
        }
    }
    // D: row = c_local = 4g+r, col = token -> lanes span consecutive hw: coalesced
    float* rp = out_recon + (size_t)bidx * CC * HW + hw0 + t0 + col;
    #pragma unroll
    for (int ct = 0; ct < 16; ++ct) {
        #pragma unroll
        for (int r = 0; r < 4; ++r) {
            rp[(size_t)(ct * 16 + 4 * g + r) * HW] = racc[ct][r];
        }
    }
}

// -------------------------------------------------------------- launch ----
extern "C" void kernel_launch(void* const* d_in, const int* in_sizes, int n_in,
                              void* d_out, int out_size, void* d_ws, size_t ws_size,
                              hipStream_t stream) {
    (void)in_sizes; (void)n_in; (void)out_size; (void)ws_size;
    const float* zin = (const float*)d_in[0];
    const float* mem = (const float*)d_in[1];
    float* out_recon = (float*)d_out;
    float* out_attn  = (float*)d_out + (size_t)16 * 256 * 64 * 64;  // after z_recon

    // ws: 4 x [512*256] ushort = 1 MB
    unsigned short* mn_hi = (unsigned short*)d_ws;
    unsigned short* mn_lo = mn_hi + 512 * 256;
    unsigned short* mT_hi = mn_lo + 512 * 256;
    unsigned short* mT_lo = mT_hi + 512 * 256;

    prep_k<<<dim3(512), dim3(64), 0, stream>>>(mem, mn_hi, mn_lo, mT_hi, mT_lo);
    bank_k<<<dim3(65536 / TT), dim3(256), 0, stream>>>(
        zin, mn_hi, mn_lo, mT_hi, mT_lo, out_recon, out_attn);
}